// Round 4
// baseline (255.838 us; speedup 1.0000x reference)
//
#include <hip/hip_runtime.h>

#define DEVI __device__ __forceinline__

typedef float f32x4 __attribute__((ext_vector_type(4)));
typedef unsigned int u32x4 __attribute__((ext_vector_type(4)));
typedef unsigned int u32x2 __attribute__((ext_vector_type(2)));
typedef __bf16 bf16x8 __attribute__((ext_vector_type(8)));

#define NB 4
#define CIN 256
#define CI_ 128
#define NN 4096
// (1/sqrt(128)) * log2(e)  -- baked into Q projections; attn uses exp2
#define QSCALE 0.12752792233895158f

typedef unsigned short us;

DEVI us f2bf(float f) {
  unsigned int x = __float_as_uint(f);
  x += 0x7FFFu + ((x >> 16) & 1u);
  return (us)(x >> 16);
}

DEVI unsigned cvtpk(float lo, float hi) {
  unsigned r;
  asm("v_cvt_pk_bf16_f32 %0, %1, %2" : "=v"(r) : "v"(lo), "v"(hi));
  return r;
}

DEVI float exp2fast(float x) {
#if __has_builtin(__builtin_amdgcn_exp2f)
  return __builtin_amdgcn_exp2f(x);
#else
  return exp2f(x);
#endif
}

DEVI f32x4 mfma16(u32x4 a, u32x4 b, f32x4 c) {
  return __builtin_amdgcn_mfma_f32_16x16x32_bf16(
      __builtin_bit_cast(bf16x8, a), __builtin_bit_cast(bf16x8, b), c, 0, 0, 0);
}

DEVI void gload16(const void* g, void* l) {
  __builtin_amdgcn_global_load_lds(
      (const __attribute__((address_space(1))) void*)g,
      (__attribute__((address_space(3))) void*)l, 16, 0, 0);
}

// ---------------- Kernel 0: weight f32 -> bf16 pre-cast ----------------
// wb layout: [6][32768]: hth, hph, th, ph, g, Ww
__global__ __launch_bounds__(256) void wcvt_kernel(
    const float* __restrict__ hth_w, const float* __restrict__ hph_w,
    const float* __restrict__ th_w, const float* __restrict__ ph_w,
    const float* __restrict__ g_w, const float* __restrict__ Ww,
    us* __restrict__ wb) {
  const float* srcs[6] = {hth_w, hph_w, th_w, ph_w, g_w, Ww};
  const float* s = srcs[blockIdx.y];
  us* d = wb + blockIdx.y * 32768;
  int idx = (blockIdx.x * 256 + threadIdx.x) * 4;
  f32x4 v = *(const f32x4*)(s + idx);
  u32x2 o;
  o[0] = cvtpk(v[0], v[1]);
  o[1] = cvtpk(v[2], v[3]);
  *(u32x2*)(d + idx) = o;
}

// ---------------- Kernel A: 5 projection GEMMs ----------------
// hqT,hkT,thT,phT stored [b][n][ci] bf16 ; g stored [b][ci][n] bf16
// hqT and thT are pre-scaled by QSCALE (so attention uses exp2 directly).
__global__ __launch_bounds__(256) void proj_kernel(
    const float* __restrict__ feats, const float* __restrict__ human,
    const float* __restrict__ g_b, const float* __restrict__ th_b,
    const float* __restrict__ ph_b, const float* __restrict__ hth_b,
    const float* __restrict__ hph_b, const us* __restrict__ wb,
    us* __restrict__ hqT, us* __restrict__ hkT,
    us* __restrict__ thT, us* __restrict__ phT, us* __restrict__ gP) {
  // LDS x-tiles: [64 n][256 c] bf16, elem swizzle: c ^ ((n&15)<<3)
  __shared__ alignas(16) us xf[64 * 256];
  __shared__ alignas(16) us xh[64 * 256];
  const int t = threadIdx.x;
  const int b = blockIdx.y;
  const int n0 = blockIdx.x * 64;
  const int w = t >> 6, l = t & 63, g16 = l >> 4, l15 = l & 15;
  const int tg = t >> 4, tl = t & 15;

  for (int which = 0; which < 2; ++which) {
    const float* src = which ? human : feats;
    us* dst = which ? xh : xf;
#pragma unroll
    for (int i = 0; i < 8; ++i) {
      int p = i * 16 + tg;  // c-pair index 0..127
      const float* s0 = src + (size_t)(b * CIN + 2 * p) * NN + n0 + tl * 4;
      f32x4 v0 = *(const f32x4*)s0;
      f32x4 v1 = *(const f32x4*)(s0 + NN);
#pragma unroll
      for (int j = 0; j < 4; ++j) {
        int row = tl * 4 + j;
        *(unsigned*)((char*)dst + row * 512 + ((4 * p) ^ ((row & 15) << 4))) =
            cvtpk(v0[j], v1[j]);
      }
    }
  }
  __syncthreads();

  const float* pb[4] = {hth_b, hph_b, th_b, ph_b};
  us* pout[4] = {hqT, hkT, thT, phT};

  // Transposed projections: M = n (rows), N = ci, K = c
  u32x4 afrag[8];
  const int arow = w * 16 + l15;
  for (int p = 0; p < 4; ++p) {
    const us* tile = (p < 2) ? xh : xf;
    if (p == 0 || p == 2) {
#pragma unroll
      for (int s = 0; s < 8; ++s)
        afrag[s] = *(const u32x4*)((const char*)tile + arow * 512 +
                                   (((s << 6) | (g16 << 4)) ^ (l15 << 4)));
    }
    const us* wbp = wb + p * 32768;
    const float scl = (p == 0 || p == 2) ? QSCALE : 1.0f;
    for (int nt = 0; nt < 8; ++nt) {
      f32x4 acc = {0.f, 0.f, 0.f, 0.f};
#pragma unroll
      for (int s = 0; s < 8; ++s) {
        u32x4 bf = *(const u32x4*)(wbp + (nt * 16 + l15) * 256 + s * 32 + g16 * 8);
        acc = mfma16(afrag[s], bf, acc);
      }
      float bias = pb[p][nt * 16 + l15];
#pragma unroll
      for (int r = 0; r < 4; ++r) {
        int nrow = n0 + w * 16 + g16 * 4 + r;
        pout[p][((size_t)b * NN + nrow) * CI_ + nt * 16 + l15] =
            f2bf((acc[r] + bias) * scl);
      }
    }
  }

  // g projection: M = ci, N = n, K = c  (B-frags from xf LDS tile)
  const us* wbg = wb + 4 * 32768;
  u32x4 ag[2][8];
#pragma unroll
  for (int mt = 0; mt < 2; ++mt)
#pragma unroll
    for (int s = 0; s < 8; ++s)
      ag[mt][s] = *(const u32x4*)(wbg + (w * 32 + mt * 16 + l15) * 256 + s * 32 + g16 * 8);
  float gb[2][4];
#pragma unroll
  for (int mt = 0; mt < 2; ++mt)
#pragma unroll
    for (int r = 0; r < 4; ++r) gb[mt][r] = g_b[w * 32 + mt * 16 + g16 * 4 + r];
  for (int nt = 0; nt < 4; ++nt) {
    f32x4 acc0 = {0.f, 0.f, 0.f, 0.f}, acc1 = {0.f, 0.f, 0.f, 0.f};
#pragma unroll
    for (int s = 0; s < 8; ++s) {
      u32x4 bf = *(const u32x4*)((const char*)xf + (nt * 16 + l15) * 512 +
                                 ((s * 64 + g16 * 16) ^ (l15 << 4)));
      acc0 = mfma16(ag[0][s], bf, acc0);
      acc1 = mfma16(ag[1][s], bf, acc1);
    }
#pragma unroll
    for (int r = 0; r < 4; ++r) {
      int ci0 = w * 32 + g16 * 4 + r;
      gP[((size_t)b * CI_ + ci0) * NN + n0 + nt * 16 + l15] = f2bf(acc0[r] + gb[0][r]);
      gP[((size_t)b * CI_ + ci0 + 16) * NN + n0 + nt * 16 + l15] = f2bf(acc1[r] + gb[1][r]);
    }
  }
}

// ---------------- Kernel B: dual-path flash attention ----------------
// grid 512 = 8 (xcd: b,path) x 64 (q-chunk of 64); 256 threads = 4 waves.
// Block stages a 128-key K/V tile; wave w owns key-slice [32w,32w+32) for
// ALL 64 q. Partial Y tree-reduced through LDS at the end.
__global__ __launch_bounds__(256, 2) void attn_kernel(
    const us* __restrict__ hqT, const us* __restrict__ hkT,
    const us* __restrict__ thT, const us* __restrict__ phT,
    const us* __restrict__ gP, us* __restrict__ PY, float* __restrict__ PL) {
  __shared__ alignas(16) us sK[128 * 128];  // [key][d]   byte swz ((key&7)<<4)
  __shared__ alignas(16) us sV[128 * 128];  // [d][key]   byte swz ((d&7)<<4)
  __shared__ alignas(16) us sP[64 * 128];   // [q][key]   byte swz ((q&7)<<4)

  const int t = threadIdx.x, w = t >> 6, l = t & 63, g16 = l >> 4, l15 = l & 15;
  const int id = blockIdx.x;
  const int bp = id & 7, b = bp & 3, path = bp >> 2;
  const int q0 = (id >> 3) * 64;
  const us* Qs = (path ? thT : hqT) + (size_t)b * NN * CI_;
  const char* Kb = (const char*)((path ? phT : hkT) + (size_t)b * NN * CI_);
  const char* Vb = (const char*)(gP + (size_t)b * CI_ * NN);

  // Q fragments: 4 q-subtiles x 4 k-slices (same lane layout for A and B)
  u32x4 aQ[4][4];
#pragma unroll
  for (int qs = 0; qs < 4; ++qs)
#pragma unroll
    for (int s = 0; s < 4; ++s)
      aQ[qs][s] = *(const u32x4*)(Qs + (size_t)(q0 + qs * 16 + l15) * CI_ +
                                  s * 32 + g16 * 8);

  f32x4 Y[4][8];
#pragma unroll
  for (int qs = 0; qs < 4; ++qs)
#pragma unroll
    for (int dt = 0; dt < 8; ++dt) Y[qs][dt] = {0.f, 0.f, 0.f, 0.f};
  float lsum[4] = {0.f, 0.f, 0.f, 0.f};

  const int rr = w * 32 + (l >> 4);  // staging row base (+4 per iter)
  const int uK = l & 15;             // 16B unit within row

  auto stage = [&](int k0) {
#pragma unroll
    for (int i = 0; i < 8; ++i) {
      int row = rr + i * 4;
      int su = (uK ^ (row & 7)) << 4;
      gload16(Kb + (((size_t)(k0 + row)) << 8) + su,
              (char*)sK + ((w * 8 + i) << 10));
      gload16(Vb + ((size_t)row << 13) + ((size_t)k0 << 1) + su,
              (char*)sV + ((w * 8 + i) << 10));
    }
  };

  stage(0);
  __syncthreads();

  for (int kt = 0; kt < 32; ++kt) {
    // ---- QK^T (swapped: mfma(K, Q) -> D[key][q], col q = l15) + exp + P-write
#pragma unroll
    for (int kk = 0; kk < 2; ++kk) {
      const int krow = 32 * w + kk * 16 + l15;
      u32x4 ak[4];
#pragma unroll
      for (int s = 0; s < 4; ++s)
        ak[s] = *(const u32x4*)((const char*)sK + krow * 256 +
                                ((s * 64 + g16 * 16) ^ ((l15 & 7) << 4)));
      f32x4 acc[4];
#pragma unroll
      for (int qs = 0; qs < 4; ++qs) acc[qs] = {0.f, 0.f, 0.f, 0.f};
      __builtin_amdgcn_s_setprio(1);
#pragma unroll
      for (int s = 0; s < 4; ++s)
#pragma unroll
        for (int qs = 0; qs < 4; ++qs)
          acc[qs] = mfma16(ak[s], aQ[qs][s], acc[qs]);
      __builtin_amdgcn_s_setprio(0);
#pragma unroll
      for (int qs = 0; qs < 4; ++qs) {
#pragma unroll
        for (int r = 0; r < 4; ++r) {
          float p = exp2fast(acc[qs][r]);
          lsum[qs] += p;
          acc[qs][r] = p;
        }
        u32x2 pw;
        pw[0] = cvtpk(acc[qs][0], acc[qs][1]);
        pw[1] = cvtpk(acc[qs][2], acc[qs][3]);
        int q = qs * 16 + l15;
        *(u32x2*)((char*)sP + q * 256 +
                  ((64 * w + kk * 32 + g16 * 8) ^ ((l15 & 7) << 4))) = pw;
      }
    }
    // ---- P A-frags (same-wave RAW; compiler inserts lgkmcnt)
    u32x4 aP[4];
#pragma unroll
    for (int qs = 0; qs < 4; ++qs) {
      int q = qs * 16 + l15;
      aP[qs] = *(const u32x4*)((const char*)sP + q * 256 +
                               ((64 * w + g16 * 16) ^ ((l15 & 7) << 4)));
    }
    // ---- PV over this wave's 32-key slice
    __builtin_amdgcn_s_setprio(1);
#pragma unroll
    for (int dt = 0; dt < 8; ++dt) {
      int vrow = dt * 16 + l15;
      u32x4 bv = *(const u32x4*)((const char*)sV + vrow * 256 +
                                 ((64 * w + g16 * 16) ^ ((l15 & 7) << 4)));
#pragma unroll
      for (int qs = 0; qs < 4; ++qs) Y[qs][dt] = mfma16(aP[qs], bv, Y[qs][dt]);
    }
    __builtin_amdgcn_s_setprio(0);
    __syncthreads();  // all waves done reading this tile
    if (kt < 31) {
      stage((kt + 1) * 128);
      __syncthreads();  // staged tile visible
    }
  }

  // ---------------- epilogue: cross-wave reduce + output ----------------
  // lsum: reduce across g16 groups -> psum[w][q]
  float* psum = (float*)sP;  // [4][64] f32 (sP no longer needed)
#pragma unroll
  for (int qs = 0; qs < 4; ++qs) {
    float v = lsum[qs];
    v += __shfl_xor(v, 16);
    v += __shfl_xor(v, 32);
    lsum[qs] = v;
  }
  if (g16 == 0) {
#pragma unroll
    for (int qs = 0; qs < 4; ++qs) psum[w * 64 + qs * 16 + l15] = lsum[qs];
  }

  // Y partials: [d][q] f32 tiles, byte swz ((d&7)<<4). regA=sK, regB=sV.
  float* regA = (float*)sK;
  float* regB = (float*)sV;
  auto ywrite = [&](float* reg) {
#pragma unroll
    for (int qs = 0; qs < 4; ++qs)
#pragma unroll
      for (int dt = 0; dt < 8; ++dt) {
        int d = dt * 16 + l15;
        *(f32x4*)((char*)reg + d * 256 +
                  ((qs * 64 + g16 * 16) ^ ((l15 & 7) << 4))) = Y[qs][dt];
      }
  };
  auto yadd = [&](const float* reg) {
#pragma unroll
    for (int qs = 0; qs < 4; ++qs)
#pragma unroll
      for (int dt = 0; dt < 8; ++dt) {
        int d = dt * 16 + l15;
        f32x4 v = *(const f32x4*)((const char*)reg + d * 256 +
                                  ((qs * 64 + g16 * 16) ^ ((l15 & 7) << 4)));
        Y[qs][dt] += v;
      }
  };

  if (w >= 2) ywrite(w == 2 ? regA : regB);
  __syncthreads();
  if (w == 0) yadd(regA);
  if (w == 1) {
    yadd(regB);
    ywrite(regB);
  }
  if (w == 3) {
    float s = psum[l] + psum[64 + l] + psum[128 + l] + psum[192 + l];
    PL[(size_t)bp * NN + q0 + l] = s;
  }
  __syncthreads();
  if (w == 0) {
    yadd(regB);
    ywrite(regA);
  }
  __syncthreads();
  // transpose-read final [d][q] and write PY [q][d] bf16
  {
    const int q = l;
#pragma unroll
    for (int o = 0; o < 4; ++o) {
      float vals[8];
#pragma unroll
      for (int j = 0; j < 8; ++j) {
        int d = w * 32 + o * 8 + j;
        vals[j] = *(const float*)((const char*)regA + d * 256 +
                                  ((q * 4) ^ ((d & 7) << 4)));
      }
      u32x4 pk;
#pragma unroll
      for (int e = 0; e < 4; ++e) pk[e] = cvtpk(vals[2 * e], vals[2 * e + 1]);
      *(u32x4*)((char*)PY + (size_t)bp * (NN * CI_ * 2) +
                (size_t)(q0 + q) * 256 + w * 64 + o * 16) = pk;
    }
  }
}

// ---------------- Kernel C: combine + W conv + BN ----------------
__global__ __launch_bounds__(256) void wout_kernel(
    const us* __restrict__ PY, const float* __restrict__ PL,
    const us* __restrict__ wb, const float* __restrict__ Wb,
    const float* __restrict__ gamma, const float* __restrict__ beta,
    const float* __restrict__ mean, const float* __restrict__ var,
    float* __restrict__ out) {
  __shared__ alignas(16) us sY[64 * 128];  // [n][ci], byte swz ((n&7)<<4)
  const int t = threadIdx.x, w = t >> 6, l = t & 63, g16 = l >> 4, l15 = l & 15;
  const int n0 = blockIdx.x * 64;
  const int ob = blockIdx.y * 64;
  const int b = blockIdx.z;

  // ---- combine paths, normalize -> bf16 LDS tile
  {
    const int row = t >> 2, cg = t & 3;
    const int n = n0 + row;
    float acc[32];
#pragma unroll
    for (int e = 0; e < 32; ++e) acc[e] = 0.f;
#pragma unroll
    for (int p = 0; p < 2; ++p) {
      int bpi = p * 4 + b;
      float sc = 0.5f / PL[(size_t)bpi * NN + n];
      const us* src = PY + (size_t)bpi * (NN * CI_) + (size_t)n * CI_ + cg * 32;
#pragma unroll
      for (int j = 0; j < 4; ++j) {
        u32x4 v = *(const u32x4*)(src + j * 8);
#pragma unroll
        for (int e = 0; e < 4; ++e) {
          unsigned u = v[e];
          acc[j * 8 + 2 * e] += __uint_as_float(u << 16) * sc;
          acc[j * 8 + 2 * e + 1] += __uint_as_float(u & 0xFFFF0000u) * sc;
        }
      }
    }
#pragma unroll
    for (int j = 0; j < 4; ++j) {
      u32x4 o;
#pragma unroll
      for (int e = 0; e < 4; ++e)
        o[e] = cvtpk(acc[j * 8 + 2 * e], acc[j * 8 + 2 * e + 1]);
      *(u32x4*)((char*)sY + row * 256 + ((cg * 64 + j * 16) ^ ((row & 7) << 4))) = o;
    }
  }

  const us* wbw = wb + 5 * 32768;
  u32x4 aW[4];
  const int orow = ob + w * 16 + l15;
#pragma unroll
  for (int s = 0; s < 4; ++s)
    aW[s] = *(const u32x4*)(wbw + orow * 128 + s * 32 + g16 * 8);
  float wbias[4], inv_[4], mu[4], bt[4];
#pragma unroll
  for (int r = 0; r < 4; ++r) {
    int o = ob + w * 16 + g16 * 4 + r;
    wbias[r] = Wb[o];
    inv_[r] = gamma[o] * rsqrtf(var[o] + 1e-5f);
    mu[r] = mean[o];
    bt[r] = beta[o];
  }
  __syncthreads();

  for (int nt = 0; nt < 4; ++nt) {
    f32x4 acc = {0.f, 0.f, 0.f, 0.f};
#pragma unroll
    for (int s = 0; s < 4; ++s) {
      u32x4 bf = *(const u32x4*)((const char*)sY + (nt * 16 + l15) * 256 +
                                 (((s << 6) | (g16 << 4)) ^ ((l15 & 7) << 4)));
      acc = mfma16(aW[s], bf, acc);
    }
#pragma unroll
    for (int r = 0; r < 4; ++r) {
      int o = ob + w * 16 + g16 * 4 + r;
      out[((size_t)b * CIN + o) * NN + n0 + nt * 16 + l15] =
          (acc[r] + wbias[r] - mu[r]) * inv_[r] + bt[r];
    }
  }
}

extern "C" void kernel_launch(void* const* d_in, const int* in_sizes, int n_in,
                              void* d_out, int out_size, void* d_ws, size_t ws_size,
                              hipStream_t stream) {
  const float* feats = (const float*)d_in[0];
  const float* human = (const float*)d_in[1];
  const float* g_w = (const float*)d_in[2];
  const float* g_b = (const float*)d_in[3];
  const float* th_w = (const float*)d_in[4];
  const float* th_b = (const float*)d_in[5];
  const float* ph_w = (const float*)d_in[6];
  const float* ph_b = (const float*)d_in[7];
  const float* hth_w = (const float*)d_in[8];
  const float* hth_b = (const float*)d_in[9];
  const float* hph_w = (const float*)d_in[10];
  const float* hph_b = (const float*)d_in[11];
  const float* Ww = (const float*)d_in[12];
  const float* Wb = (const float*)d_in[13];
  const float* gamma = (const float*)d_in[14];
  const float* beta = (const float*)d_in[15];
  const float* mean = (const float*)d_in[16];
  const float* var = (const float*)d_in[17];

  us* ws = (us*)d_ws;
  const size_t SZ = (size_t)NB * NN * CI_;  // 2,097,152 us per projection
  us* hqT = ws;
  us* hkT = ws + SZ;
  us* thT = ws + 2 * SZ;
  us* phT = ws + 3 * SZ;
  us* gP = ws + 4 * SZ;
  us* PY = ws + 5 * SZ;                          // 8 * NN * CI_ us = 4,194,304 us
  float* PL = (float*)(ws + 5 * SZ + 4194304);   // 8*NN f32 = 65,536 us
  us* wb = ws + 5 * SZ + 4194304 + 65536;        // 6*32768 us

  wcvt_kernel<<<dim3(32, 6), 256, 0, stream>>>(hth_w, hph_w, th_w, ph_w, g_w, Ww, wb);
  proj_kernel<<<dim3(64, 4), 256, 0, stream>>>(feats, human, g_b, th_b, ph_b,
                                               hth_b, hph_b, wb, hqT, hkT, thT,
                                               phT, gP);
  attn_kernel<<<512, 256, 0, stream>>>(hqT, hkT, thT, phT, gP, PY, PL);
  wout_kernel<<<dim3(64, 4, 4), 256, 0, stream>>>(PY, PL, wb, Wb, gamma, beta,
                                                  mean, var, (float*)d_out);
}